// Round 10
// baseline (1808.472 us; speedup 1.0000x reference)
//
#include <hip/hip_runtime.h>
#include <math.h>

// ---------------------------------------------------------------------------
// MemoryLayerAttention: 8-step recurrent transformer cell.
//   N=128 sequences, L=257 rows, E=32, CH=4 heads, KD=32, FF=128, R=256, C=32.
// Per step (graph-captured):
//   k_attn   : FUSED proj+attention. One block per (n,h); phase 1 computes
//              K,V for all 257 keys into LDS (z is L2-hot, recompute beats
//              the 50MB scratch round-trip); phase 3 streams keys via
//              uniform broadcast ds_read_b128 with double-buffered prefetch.
//   k_ffln   : block=64 rows x 4 FF-quarters; balanced all-wave merge
//   k_memaug : block=64 rows x 4 col-quarters; mnew exchanged via LDS
// ---------------------------------------------------------------------------

#define L_SEQ 257
#define SCALE 0.17677669529663689f   // 1/sqrt(32)

// ws layout (floats)
#define MEM_SZ  (128*256*32)
#define Z_SZ    (128*257*32)
#define HO_SZ   (128*4*257*32)
#define NF_SZ   (128*257*32)
#define PE_SZ   (L_SEQ*32)

// K and V in LDS: 257 rows each, padded to 36 floats (144B, 16B-aligned;
// pad keeps per-lane-row tail reads at 8-way instead of 64-way conflicts).
#define KV_LDS_BYTES (2*L_SEQ*9*16)   // 74016 B -> 2 blocks/CU

// ---------------------------------------------------------------------------
__global__ void k_init(float* __restrict__ mem) {
  const int i = blockIdx.x*256 + threadIdx.x;
  if (i < MEM_SZ) mem[i] = 1e-6f;
}

// PE computed in double to match numpy's float64 path; runs once per call.
__global__ void k_pe(float* __restrict__ pe) {
  const int i = blockIdx.x*256 + threadIdx.x;
  if (i >= L_SEQ*32) return;
  const int row = i >> 5, e = i & 31;
  const int k = e >> 1;
  const double p10 = pow(10000.0, (double)(2*k)/32.0);
  const double ang = (double)row / p10;
  pe[i] = (float)((e & 1) ? cos(ang) : sin(ang));
}

// ---------------------------------------------------------------------------
// t=0 only. grid (129, 4): blockIdx.y = e-quarter (uniform weight reads)
__global__ __launch_bounds__(256, 2)
void k_aug(const float* __restrict__ queries, const float* __restrict__ values,
           const float* __restrict__ W_in, const float* __restrict__ b_in,
           const float* __restrict__ W_me, const float* __restrict__ b_me,
           const float* __restrict__ mem, const float* __restrict__ pe,
           float* __restrict__ z, int t) {
  const int gid = blockIdx.x*256 + threadIdx.x;
  if (gid >= 128*L_SEQ) return;
  const int e0 = blockIdx.y * 8;
  const int n = gid / L_SEQ, row = gid - n*L_SEQ;
  float acc[8];
  if (row == 0) {
    #pragma unroll
    for (int k = 0; k < 8; k++) acc[k] = b_in[e0+k];
    const float* q = queries + n*32;
    const float* v = values + (size_t)((n>>2)*8 + t)*32;
    for (int c = 0; c < 32; c++) {
      const float qc = q[c], vc = v[c];
      #pragma unroll
      for (int k = 0; k < 8; k++) acc[k] += qc*W_in[c*32+e0+k] + vc*W_in[(32+c)*32+e0+k];
    }
  } else {
    #pragma unroll
    for (int k = 0; k < 8; k++) acc[k] = b_me[e0+k];
    const float* mr = mem + ((size_t)n*256 + (row-1))*32;
    for (int c = 0; c < 32; c++) {
      const float mc = mr[c];
      #pragma unroll
      for (int k = 0; k < 8; k++) acc[k] += mc*W_me[c*32+e0+k];
    }
  }
  float* zr = z + (size_t)gid*32 + e0;
  const float* per = pe + row*32 + e0;
  #pragma unroll
  for (int k = 0; k < 8; k++) zr[k] = acc[k] + per[k];
}

// ---------------------------------------------------------------------------
// Fused projection + attention. grid 512 (= nh), 256 threads, 2 blocks/CU
// fully co-resident. Lane tid owns query row tid; row 256 by wave 0 tail.
__global__ __launch_bounds__(256, 2)
void k_attn(const float* __restrict__ z,
            const float* __restrict__ Wq, const float* __restrict__ bq,
            const float* __restrict__ Wk, const float* __restrict__ bk,
            const float* __restrict__ Wv, const float* __restrict__ bv,
            const float* __restrict__ Wo,
            float* __restrict__ headout) {
  extern __shared__ float4 KV4[];    // K rows [0,257), V rows [257,514), 9 f4/row
  const int nh = blockIdx.x;
  const int n = nh >> 2, h = nh & 3;
  const int tid = threadIdx.x;
  const float* zb = z + (size_t)n*L_SEQ*32;
  const float* wo = Wo + h*1024;
  float* hob = headout + (size_t)nh*L_SEQ*32;

  // ---- phase 1: K,V for all 257 keys -> LDS (514 row-tasks / 256 threads)
  for (int task = tid; task < 2*L_SEQ; task += 256) {
    const int isv = task >= L_SEQ;
    const int j = isv ? task - L_SEQ : task;
    const float* W  = isv ? Wv : Wk;
    const float* bb = isv ? bv : bk;
    float acc[32];
    #pragma unroll
    for (int d = 0; d < 32; d++) acc[d] = bb[h*32+d];
    const float4* zr = (const float4*)(zb + (size_t)j*32);
    #pragma unroll 2
    for (int c8 = 0; c8 < 8; c8++) {
      const float4 zc = zr[c8];
      const float zv[4] = {zc.x, zc.y, zc.z, zc.w};
      #pragma unroll
      for (int qq = 0; qq < 4; qq++) {
        const int e = c8*4 + qq;
        const float ze = zv[qq];
        #pragma unroll
        for (int d = 0; d < 32; d++) acc[d] += ze * W[e*128 + h*32 + d];
      }
    }
    float4* dst = KV4 + (size_t)(isv*L_SEQ + j)*9;
    #pragma unroll
    for (int c = 0; c < 8; c++)
      dst[c] = make_float4(acc[4*c], acc[4*c+1], acc[4*c+2], acc[4*c+3]);
  }

  // ---- phase 2: q for own row (row = tid), pre-scaled
  float q[32];
  {
    #pragma unroll
    for (int d = 0; d < 32; d++) q[d] = bq[h*32+d];
    const float4* zr = (const float4*)(zb + (size_t)tid*32);
    #pragma unroll 2
    for (int c8 = 0; c8 < 8; c8++) {
      const float4 zc = zr[c8];
      const float zv[4] = {zc.x, zc.y, zc.z, zc.w};
      #pragma unroll
      for (int qq = 0; qq < 4; qq++) {
        const int e = c8*4 + qq;
        const float ze = zv[qq];
        #pragma unroll
        for (int d = 0; d < 32; d++) q[d] += ze * Wq[e*128 + h*32 + d];
      }
    }
    #pragma unroll
    for (int d = 0; d < 32; d++) q[d] *= SCALE;
  }
  __syncthreads();

  // ---- phase 3: online softmax over 257 keys, double-buffered LDS reads
  float o[32];
  #pragma unroll
  for (int d = 0; d < 32; d++) o[d] = 0.f;
  float m = -1e30f, sum = 0.f;
  float4 Ka[8], Va[8], Kb2[8], Vb2[8];
  #pragma unroll
  for (int c = 0; c < 8; c++) { Ka[c] = KV4[c]; Va[c] = KV4[L_SEQ*9 + c]; }

#define PROC(K_, V_) { \
    float s0=0.f,s1=0.f,s2=0.f,s3=0.f; \
    _Pragma("unroll") \
    for (int c = 0; c < 8; c++) { \
      s0 += q[4*c]*K_[c].x;   s1 += q[4*c+1]*K_[c].y; \
      s2 += q[4*c+2]*K_[c].z; s3 += q[4*c+3]*K_[c].w; } \
    const float x = (s0+s1)+(s2+s3); \
    if (!__all(x <= m)) { \
      const float nm = fmaxf(m, x); \
      const float e0 = __expf(m - nm); \
      sum *= e0; \
      _Pragma("unroll") \
      for (int d = 0; d < 32; d++) o[d] *= e0; \
      m = nm; } \
    const float p = __expf(x - m); \
    sum += p; \
    _Pragma("unroll") \
    for (int c = 0; c < 8; c++) { \
      o[4*c]   += p*V_[c].x; o[4*c+1] += p*V_[c].y; \
      o[4*c+2] += p*V_[c].z; o[4*c+3] += p*V_[c].w; } }

  #pragma unroll 1
  for (int i = 0; i < 128; i++) {
    const int l0 = 2*i;
    #pragma unroll
    for (int c = 0; c < 8; c++) {
      Kb2[c] = KV4[(l0+1)*9 + c];
      Vb2[c] = KV4[(L_SEQ + l0+1)*9 + c];
    }
    PROC(Ka, Va);                 // key l0
    #pragma unroll
    for (int c = 0; c < 8; c++) {
      Ka[c] = KV4[(l0+2)*9 + c];
      Va[c] = KV4[(L_SEQ + l0+2)*9 + c];
    }
    PROC(Kb2, Vb2);               // key l0+1
  }
  PROC(Ka, Va);                   // key 256
#undef PROC

  // ---- phase 4: Wo projection (uniform weights), write own row
  {
    const float inv = 1.f/sum;
    float outv[32];
    #pragma unroll 4
    for (int d = 0; d < 32; d++) {
      float a = 0.f;
      #pragma unroll
      for (int kd = 0; kd < 32; kd++) a += o[kd]*wo[kd*32 + d];
      outv[d] = a*inv;
    }
    float4* dst = (float4*)(hob + (size_t)tid*32);
    #pragma unroll
    for (int c = 0; c < 8; c++)
      dst[c] = make_float4(outv[4*c], outv[4*c+1], outv[4*c+2], outv[4*c+3]);
  }

  // ---- phase 5: query row 256 (wave 0; lanes split keys; butterfly merge)
  if (tid < 64) {
    const int lane = tid;
    float q2[32];
    #pragma unroll
    for (int d = 0; d < 32; d++) q2[d] = bq[h*32+d];
    const float* z2 = zb + 256*32;        // uniform -> scalar loads
    for (int e = 0; e < 32; e++) {
      const float a = z2[e];
      #pragma unroll
      for (int d = 0; d < 32; d++) q2[d] += a * Wq[e*128 + h*32 + d];
    }
    #pragma unroll
    for (int d = 0; d < 32; d++) q2[d] *= SCALE;
    float m2 = -1e30f, s2 = 0.f, o2[32];
    #pragma unroll
    for (int d = 0; d < 32; d++) o2[d] = 0.f;
    for (int l = lane; l < L_SEQ; l += 64) {
      const float4* kr = KV4 + (size_t)l*9;           // per-lane rows: 8-way
      const float4* vr = KV4 + (size_t)(L_SEQ+l)*9;   // (pad-36 swizzle)
      float s0=0.f,s1=0.f,sp=0.f,s3=0.f; float vv[32];
      #pragma unroll
      for (int c = 0; c < 8; c++) {
        const float4 kc = kr[c];
        s0 += q2[4*c]*kc.x;   s1 += q2[4*c+1]*kc.y;
        sp += q2[4*c+2]*kc.z; s3 += q2[4*c+3]*kc.w;
        const float4 vc = vr[c];
        vv[4*c]=vc.x; vv[4*c+1]=vc.y; vv[4*c+2]=vc.z; vv[4*c+3]=vc.w;
      }
      const float x = (s0+s1)+(sp+s3);
      const float nm = fmaxf(m2, x);
      const float e0 = __expf(m2-nm), p = __expf(x-nm);
      s2 = s2*e0 + p;
      #pragma unroll
      for (int d = 0; d < 32; d++) o2[d] = o2[d]*e0 + p*vv[d];
      m2 = nm;
    }
    #pragma unroll 1
    for (int off = 1; off < 64; off <<= 1) {
      const float om = __shfl_xor(m2, off);
      const float os = __shfl_xor(s2, off);
      const float nm = fmaxf(m2, om);
      const float me = __expf(m2-nm), oe = __expf(om-nm);
      s2 = s2*me + os*oe;
      #pragma unroll
      for (int d = 0; d < 32; d++) o2[d] = o2[d]*me + __shfl_xor(o2[d], off)*oe;
      m2 = nm;
    }
    if (lane < 32) {
      float a = 0.f;
      #pragma unroll
      for (int kd = 0; kd < 32; kd++) a += o2[kd]*wo[kd*32 + lane];
      hob[256*32 + lane] = a / s2;
    }
  }
}

// ---------------------------------------------------------------------------
// grid 514 x 256. Block = 64 rows; wave w computes FF units [w*32, w*32+32);
// all waves stash to LDS, merge redundantly, each writes its 8-float quarter.
__global__ __launch_bounds__(256, 4)
void k_ffln(const float* __restrict__ headout, const float* __restrict__ z,
            const float* __restrict__ bo,
            const float* __restrict__ W_f1, const float* __restrict__ b_f1,
            const float* __restrict__ W_f2, const float* __restrict__ b_f2,
            const float* __restrict__ ln_g, const float* __restrict__ ln_b,
            const float* __restrict__ W_out, const float* __restrict__ b_out,
            float* __restrict__ nf, float* __restrict__ outp, int t) {
  __shared__ float ybuf[4][64][33];
  const int tid = threadIdx.x;
  const int wave = __builtin_amdgcn_readfirstlane(tid >> 6);  // uniform!
  const int lane = tid & 63;
  const int rowid = blockIdx.x*64 + lane;             // 514*64 = 32896 exact
  const int n = rowid / L_SEQ, row = rowid - n*L_SEQ;

  float att[32];
  const float* hob = headout + (size_t)n*4*L_SEQ*32 + (size_t)row*32;
  const float* zr = z + (size_t)rowid*32;
  #pragma unroll
  for (int e = 0; e < 32; e++)
    att[e] = bo[e] + zr[e] + hob[e] + hob[L_SEQ*32 + e]
           + hob[2*L_SEQ*32 + e] + hob[3*L_SEQ*32 + e];
  float mu = 0.f;
  #pragma unroll
  for (int e = 0; e < 32; e++) mu += att[e];
  mu *= (1.f/32.f);
  float var = 0.f;
  #pragma unroll
  for (int e = 0; e < 32; e++) { const float d = att[e]-mu; var += d*d; }
  var *= (1.f/32.f);
  float rstd = 1.f/sqrtf(var + 1e-6f);
  #pragma unroll
  for (int e = 0; e < 32; e++) att[e] = (att[e]-mu)*rstd*ln_g[e] + ln_b[e];

  // FF quarter: j in [wave*32, wave*32+32)
  float y[32];
  #pragma unroll
  for (int e = 0; e < 32; e++) y[e] = 0.f;
  const int j0 = wave*32;
  #pragma unroll 1
  for (int jj = 0; jj < 32; jj++) {
    const int j = j0 + jj;
    float hv = b_f1[j];
    #pragma unroll
    for (int e = 0; e < 32; e++) hv += att[e]*W_f1[e*128 + j];
    hv = fmaxf(hv, 0.f);
    #pragma unroll
    for (int e = 0; e < 32; e++) y[e] += hv*W_f2[j*32 + e];
  }
  #pragma unroll
  for (int e = 0; e < 32; e++) ybuf[wave][lane][e] = y[e];
  __syncthreads();

  #pragma unroll
  for (int e = 0; e < 32; e++)
    y[e] = ybuf[0][lane][e] + ybuf[1][lane][e] + ybuf[2][lane][e]
         + ybuf[3][lane][e] + b_f2[e] + att[e];

  mu = 0.f;
  #pragma unroll
  for (int e = 0; e < 32; e++) mu += y[e];
  mu *= (1.f/32.f);
  var = 0.f;
  #pragma unroll
  for (int e = 0; e < 32; e++) { const float d = y[e]-mu; var += d*d; }
  var *= (1.f/32.f);
  rstd = 1.f/sqrtf(var + 1e-6f);
  float nfv[32];
  #pragma unroll
  for (int e = 0; e < 32; e++) nfv[e] = (y[e]-mu)*rstd*ln_g[e] + ln_b[e];

  float4* nr = (float4*)(nf + (size_t)rowid*32 + wave*8);
  nr[0] = make_float4(nfv[wave*8+0], nfv[wave*8+1], nfv[wave*8+2], nfv[wave*8+3]);
  nr[1] = make_float4(nfv[wave*8+4], nfv[wave*8+5], nfv[wave*8+6], nfv[wave*8+7]);

  if (t == 7 && row == 0 && wave == 0) {
    float a = b_out[0];
    #pragma unroll
    for (int e = 0; e < 32; e++) a += nfv[e]*W_out[e];
    outp[n] = a;
  }
}

// ---------------------------------------------------------------------------
// grid 514 x 256. Block = 64 z-rows; wave w computes mi/mnew columns
// [w*8, w*8+8) (wave-uniform W_mi reads), mnew exchanged via LDS, then z
// e-quarter per wave. Row-0 lanes take the W_in embed path in phase 2.
__global__ __launch_bounds__(256, 4)
void k_memaug(const float* __restrict__ queries, const float* __restrict__ values,
              const float* __restrict__ W_in, const float* __restrict__ b_in,
              const float* __restrict__ W_me, const float* __restrict__ b_me,
              const float* __restrict__ W_mi, const float* __restrict__ b_mi,
              const float* __restrict__ nf, const float* __restrict__ pe,
              float* __restrict__ mem, float* __restrict__ z, int tnext) {
  __shared__ float mbuf[64][33];
  const int tid = threadIdx.x;
  const int wave = __builtin_amdgcn_readfirstlane(tid >> 6);  // uniform!
  const int lane = tid & 63;
  const int rowid = blockIdx.x*64 + lane;             // 514*64 = 32896 exact
  const int n = rowid / L_SEQ, row = rowid - n*L_SEQ;
  const int e0 = wave*8;
  const bool isrow0 = (row == 0);

  if (!isrow0) {
    float xr[32];
    const float4* x4 = (const float4*)(nf + (size_t)rowid*32);
    #pragma unroll
    for (int c = 0; c < 8; c++) {
      const float4 t4 = x4[c];
      xr[4*c] = t4.x; xr[4*c+1] = t4.y; xr[4*c+2] = t4.z; xr[4*c+3] = t4.w;
    }
    float mi0 = b_mi[0];
    #pragma unroll
    for (int e = 0; e < 32; e++) mi0 += xr[e]*W_mi[e*33];
    const float cs = 1.f/(1.f + expf(-mi0));
    const float ga = 1.f/(1.f + expf(cs));    // sigmoid(-cs)
    const float gb = 1.f/(1.f + expf(-cs));   // sigmoid(cs)
    float* mr = mem + ((size_t)n*256 + (row-1))*32 + e0;
    float mnew[8];
    #pragma unroll
    for (int cc = 0; cc < 8; cc++) {
      const int c = e0 + cc;
      float mic = b_mi[1+c];
      #pragma unroll
      for (int e = 0; e < 32; e++) mic += xr[e]*W_mi[e*33 + 1 + c];
      mnew[cc] = ga*mr[cc] + gb*mic;
    }
    ((float4*)mr)[0] = make_float4(mnew[0], mnew[1], mnew[2], mnew[3]);
    ((float4*)mr)[1] = make_float4(mnew[4], mnew[5], mnew[6], mnew[7]);
    #pragma unroll
    for (int cc = 0; cc < 8; cc++) mbuf[lane][e0+cc] = mnew[cc];
  }
  __syncthreads();

  float acc[8];
  if (isrow0) {
    #pragma unroll
    for (int k = 0; k < 8; k++) acc[k] = b_in[e0+k];
    const float* q = queries + n*32;
    const float* v = values + (size_t)((n>>2)*8 + tnext)*32;
    for (int c = 0; c < 32; c++) {
      const float qc = q[c], vc = v[c];
      #pragma unroll
      for (int k = 0; k < 8; k++) acc[k] += qc*W_in[c*32+e0+k] + vc*W_in[(32+c)*32+e0+k];
    }
  } else {
    #pragma unroll
    for (int k = 0; k < 8; k++) acc[k] = b_me[e0+k];
    #pragma unroll 4
    for (int c = 0; c < 32; c++) {
      const float mc = mbuf[lane][c];
      #pragma unroll
      for (int k = 0; k < 8; k++) acc[k] += mc*W_me[c*32+e0+k];
    }
  }
  const float* per = pe + row*32 + e0;
  float4* zr = (float4*)(z + (size_t)rowid*32 + e0);
  zr[0] = make_float4(acc[0]+per[0], acc[1]+per[1], acc[2]+per[2], acc[3]+per[3]);
  zr[1] = make_float4(acc[4]+per[4], acc[5]+per[5], acc[6]+per[6], acc[7]+per[7]);
}

// ---------------------------------------------------------------------------
extern "C" void kernel_launch(void* const* d_in, const int* in_sizes, int n_in,
                              void* d_out, int out_size, void* d_ws, size_t ws_size,
                              hipStream_t stream) {
  const float* queries = (const float*)d_in[0];
  const float* values  = (const float*)d_in[1];
  const float* W_in = (const float*)d_in[2];   const float* b_in = (const float*)d_in[3];
  const float* W_me = (const float*)d_in[4];   const float* b_me = (const float*)d_in[5];
  const float* Wq   = (const float*)d_in[6];   const float* bq   = (const float*)d_in[7];
  const float* Wk   = (const float*)d_in[8];   const float* bk   = (const float*)d_in[9];
  const float* Wv   = (const float*)d_in[10];  const float* bv   = (const float*)d_in[11];
  const float* Wo   = (const float*)d_in[12];  const float* bo   = (const float*)d_in[13];
  const float* W_f1 = (const float*)d_in[14];  const float* b_f1 = (const float*)d_in[15];
  const float* W_f2 = (const float*)d_in[16];  const float* b_f2 = (const float*)d_in[17];
  const float* ln_g = (const float*)d_in[18];  const float* ln_b = (const float*)d_in[19];
  const float* W_out= (const float*)d_in[20];  const float* b_out= (const float*)d_in[21];
  const float* W_mi = (const float*)d_in[22];  const float* b_mi = (const float*)d_in[23];

  float* ws  = (float*)d_ws;
  float* mem = ws;                 // MEM_SZ
  float* z   = mem + MEM_SZ;       // Z_SZ
  float* ho  = z   + Z_SZ;         // HO_SZ
  float* nf  = ho  + HO_SZ;        // NF_SZ
  float* pe  = nf  + NF_SZ;        // PE_SZ
  float* outp = (float*)d_out;     // 128 floats

  // raise dynamic-LDS cap for k_attn (74 KB > 64 KB default); idempotent.
  hipFuncSetAttribute((const void*)k_attn,
                      hipFuncAttributeMaxDynamicSharedMemorySize, KV_LDS_BYTES);

  k_init<<<MEM_SZ/256, 256, 0, stream>>>(mem);
  k_pe<<<(L_SEQ*32 + 255)/256, 256, 0, stream>>>(pe);
  k_aug<<<dim3(129, 4), 256, 0, stream>>>(queries, values, W_in, b_in,
                                          W_me, b_me, mem, pe, z, 0);
  for (int t = 0; t < 8; t++) {
    k_attn<<<512, 256, KV_LDS_BYTES, stream>>>(z, Wq, bq, Wk, bk, Wv, bv, Wo, ho);
    k_ffln<<<514, 256, 0, stream>>>(ho, z, bo, W_f1, b_f1, W_f2, b_f2,
                                    ln_g, ln_b, W_out, b_out, nf, outp, t);
    if (t < 7)
      k_memaug<<<514, 256, 0, stream>>>(queries, values, W_in, b_in, W_me, b_me,
                                        W_mi, b_mi, nf, pe, mem, z, t+1);
  }
}